// Round 1
// baseline (19022.070 us; speedup 1.0000x reference)
//
#include <hip/hip_runtime.h>

#define BB 64
#define TT 64
#define DD 256
#define TAA 128
#define UU 256
#define VV 50257
#define VPAD 50304
#define NBLK 512
#define NCHUNK 786  // ceil(V/64)

typedef __attribute__((ext_vector_type(8))) short bf16x8;
typedef __attribute__((ext_vector_type(4))) float floatx4;

__device__ __forceinline__ float bf2f(unsigned short u) {
  union { unsigned int i; float f; } c; c.i = ((unsigned int)u) << 16; return c.f;
}
__device__ __forceinline__ unsigned short f2bf(float f) {
  union { float f; unsigned int i; } c; c.f = f;
  return (unsigned short)((c.i + 0x7fffu + ((c.i >> 16) & 1u)) >> 16);
}
__device__ __forceinline__ float hsig(float x) {
  return fminf(1.0f, fmaxf(0.0f, 0.2f * x + 0.5f));
}

__device__ __forceinline__ void gbar(unsigned long long* bar) {
  __syncthreads();
  if (threadIdx.x == 0) {
    unsigned long long token =
        __hip_atomic_fetch_add(bar, 1ull, __ATOMIC_RELEASE, __HIP_MEMORY_SCOPE_AGENT) + 1ull;
    unsigned long long target = ((token + (unsigned long long)NBLK - 1ull) /
                                 (unsigned long long)NBLK) * (unsigned long long)NBLK;
    while (__hip_atomic_load(bar, __ATOMIC_RELAXED, __HIP_MEMORY_SCOPE_AGENT) < target)
      __builtin_amdgcn_s_sleep(2);
  }
  __syncthreads();
  __threadfence();  // acquire: invalidate stale L1/L2 before reading cross-XCD data
}

// ---------------- prep kernels ----------------

__global__ void k_f2bf(const float* __restrict__ in, unsigned short* __restrict__ out, int n) {
  int i = blockIdx.x * 256 + threadIdx.x;
  int stride = gridDim.x * 256;
  for (; i < n; i += stride) out[i] = f2bf(in[i]);
}

// W_o1 (256 x V) fp32 -> w1t (V x 256) bf16
__global__ void k_tw1(const float* __restrict__ w, unsigned short* __restrict__ o) {
  __shared__ float tile[32][33];
  const int bx = blockIdx.x, by = blockIdx.y;
  const int tx = threadIdx.x, ty = threadIdx.y;
#pragma unroll
  for (int i = 0; i < 4; ++i) {
    int k = by * 32 + ty + i * 8;
    int v = bx * 32 + tx;
    tile[ty + i * 8][tx] = (v < VV) ? w[(size_t)k * VV + v] : 0.0f;
  }
  __syncthreads();
#pragma unroll
  for (int i = 0; i < 4; ++i) {
    int v = bx * 32 + ty + i * 8;
    int k = by * 32 + tx;
    if (v < VV) o[(size_t)v * 256 + k] = f2bf(tile[tx][ty + i * 8]);
  }
}

// embedding (V x 256) fp32 -> embt (256 x VPAD) bf16
__global__ void k_temb(const float* __restrict__ e, unsigned short* __restrict__ o) {
  __shared__ float tile[32][33];
  const int bx = blockIdx.x, by = blockIdx.y;
  const int tx = threadIdx.x, ty = threadIdx.y;
#pragma unroll
  for (int i = 0; i < 4; ++i) {
    int v = bx * 32 + ty + i * 8;
    int d = by * 32 + tx;
    tile[ty + i * 8][tx] = (v < VV) ? e[(size_t)v * 256 + d] : 0.0f;
  }
  __syncthreads();
#pragma unroll
  for (int i = 0; i < 4; ++i) {
    int d = by * 32 + ty + i * 8;
    int v = bx * 32 + tx;
    if (v < VV) o[(size_t)d * VPAD + v] = f2bf(tile[tx][ty + i * 8]);
  }
}

// xp = x(4096x256) @ kernel(256x768) + bias, fp32
__global__ void k_xp(const float* __restrict__ x, const float* __restrict__ kern,
                     const float* __restrict__ bias, float* __restrict__ xp) {
  __shared__ float xs[256][20];
  const int r0 = blockIdx.x * 16;
  const int tid = threadIdx.x;
  for (int idx = tid; idx < 16 * 256; idx += 256) {
    int rr = idx >> 8;
    int k = idx & 255;
    xs[k][rr] = x[(size_t)(r0 + rr) * 256 + k];
  }
  __syncthreads();
  float acc[16][3];
#pragma unroll
  for (int rr = 0; rr < 16; ++rr) {
    acc[rr][0] = bias[tid];
    acc[rr][1] = bias[256 + tid];
    acc[rr][2] = bias[512 + tid];
  }
  for (int k = 0; k < 256; ++k) {
    float k0 = kern[k * 768 + tid];
    float k1 = kern[k * 768 + 256 + tid];
    float k2 = kern[k * 768 + 512 + tid];
#pragma unroll
    for (int rr = 0; rr < 16; ++rr) {
      float xv = xs[k][rr];
      acc[rr][0] = fmaf(xv, k0, acc[rr][0]);
      acc[rr][1] = fmaf(xv, k1, acc[rr][1]);
      acc[rr][2] = fmaf(xv, k2, acc[rr][2]);
    }
  }
  for (int rr = 0; rr < 16; ++rr) {
    xp[(size_t)(r0 + rr) * 768 + tid] = acc[rr][0];
    xp[(size_t)(r0 + rr) * 768 + 256 + tid] = acc[rr][1];
    xp[(size_t)(r0 + rr) * 768 + 512 + tid] = acc[rr][2];
  }
}

// ---------------- main persistent kernel ----------------

__global__ void __launch_bounds__(256, 2) gru_main(
    const float* __restrict__ att,            // (64,128,256) fp32
    const float* __restrict__ aab,            // after_att_bias (512) fp32
    const unsigned short* __restrict__ kbf,   // kernel bf16 (256x768)
    const unsigned short* __restrict__ rkbf,  // recurrent_kernel bf16 (256x768)
    const unsigned short* __restrict__ aabf,  // after_att_kernel bf16 (256x512)
    const float* __restrict__ xp,             // (4096x768) fp32
    const unsigned short* __restrict__ w1t,   // (VPAD x 256) bf16, rows<V valid
    const unsigned short* __restrict__ embt,  // (256 x VPAD) bf16, cols<V valid
    unsigned short* __restrict__ sbf,         // (64x256) bf16
    unsigned short* __restrict__ pfb,         // (NBLK x 64 x 256) bf16 partial fb
    float* __restrict__ psum,                 // (NBLK x 64) fp32 partial sum-exp
    unsigned long long* __restrict__ bar,
    float* __restrict__ y)                    // d_out (64,64,256) fp32
{
  __shared__ float hL[256], fbL[256], rhL[256], cL[256], s1L[256];
  __shared__ float eL[128];
  __shared__ float red4[1024];
  __shared__ float zredL[256];
  __shared__ short Plds[4][16 * 88];

  const int blk = blockIdx.x;
  const int tid = threadIdx.x;
  const int b = blk;  // batch index when blk < 64

  // attention(h) -> c -> s1 -> s2 -> sbf[b]
  auto attention = [&]() {
    if (tid < 128) {
      const float* ar = att + (size_t)(b * TAA + tid) * DD;
      float l = 0.f;
#pragma unroll 4
      for (int dd = 0; dd < DD; dd += 4) {
        float4 a4 = *reinterpret_cast<const float4*>(ar + dd);
        l += a4.x * hL[dd] + a4.y * hL[dd + 1] + a4.z * hL[dd + 2] + a4.w * hL[dd + 3];
      }
      eL[tid] = l;
    }
    __syncthreads();
    if (tid < 64) {
      float l0 = eL[tid], l1 = eL[tid + 64];
      float m = fmaxf(l0, l1);
#pragma unroll
      for (int off = 32; off > 0; off >>= 1) m = fmaxf(m, __shfl_xor(m, off));
      float e0 = __expf(l0 - m), e1 = __expf(l1 - m);
      float s = e0 + e1;
#pragma unroll
      for (int off = 32; off > 0; off >>= 1) s += __shfl_xor(s, off);
      float inv = 1.0f / s;
      eL[tid] = e0 * inv;
      eL[tid + 64] = e1 * inv;
    }
    __syncthreads();
    {
      float c = 0.f;
      const float* ab = att + (size_t)b * TAA * DD + tid;
#pragma unroll 4
      for (int ta = 0; ta < TAA; ++ta) c += eL[ta] * ab[ta * DD];
      cL[tid] = c;
    }
    __syncthreads();
    {
      float a = aab[tid];
#pragma unroll 4
      for (int k = 0; k < UU; ++k) a += cL[k] * bf2f(aabf[k * 512 + tid]);
      s1L[tid] = tanhf(a);
    }
    __syncthreads();
    {
      float a = aab[256 + tid];
#pragma unroll 4
      for (int k = 0; k < UU; ++k) a += s1L[k] * bf2f(aabf[k * 512 + 256 + tid]);
      sbf[b * 256 + tid] = (unsigned short)f2bf(tanhf(a));
    }
  };

  // combine partials -> fb; GRU gates -> h_t; write y[:,t,:]
  auto ca_step = [&](int t) {
    const int g4 = tid >> 6;
    const int dq = tid & 63;
    {
      float a0 = 0, a1 = 0, a2 = 0, a3 = 0;
      const unsigned short* base = pfb + b * 256 + dq * 4;
#pragma unroll 4
      for (int g = g4; g < NBLK; g += 4) {
        uint2 u = *reinterpret_cast<const uint2*>(base + (size_t)g * 16384);
        a0 += __uint_as_float(u.x << 16);
        a1 += __uint_as_float(u.x & 0xffff0000u);
        a2 += __uint_as_float(u.y << 16);
        a3 += __uint_as_float(u.y & 0xffff0000u);
      }
      red4[g4 * 256 + dq * 4 + 0] = a0;
      red4[g4 * 256 + dq * 4 + 1] = a1;
      red4[g4 * 256 + dq * 4 + 2] = a2;
      red4[g4 * 256 + dq * 4 + 3] = a3;
      float zp = 0.f;
      for (int g = tid; g < NBLK; g += 256) zp += psum[g * 64 + b];
      zredL[tid] = zp;
    }
    __syncthreads();
    if (tid < 64) {
      float z2 = zredL[tid] + zredL[tid + 64] + zredL[tid + 128] + zredL[tid + 192];
#pragma unroll
      for (int off = 32; off > 0; off >>= 1) z2 += __shfl_xor(z2, off);
      if (tid == 0) zredL[0] = z2;
    }
    __syncthreads();
    {
      float invZ = 1.0f / zredL[0];
      fbL[tid] = (red4[tid] + red4[256 + tid] + red4[512 + tid] + red4[768 + tid]) * invZ;
    }
    __syncthreads();
    // gates: z,r then hh with (r*h)@Uh
    const float* xprow = xp + (size_t)(b * 64 + t) * 768;
    float zpre = xprow[tid];
    float rpre = xprow[256 + tid];
#pragma unroll 2
    for (int k = 0; k < 256; ++k) {
      float fbk = fbL[k], hk = hL[k];
      const unsigned short* kp = kbf + k * 768 + tid;
      const unsigned short* up = rkbf + k * 768 + tid;
      zpre += fbk * bf2f(kp[0]) + hk * bf2f(up[0]);
      rpre += fbk * bf2f(kp[256]) + hk * bf2f(up[256]);
    }
    float r = hsig(rpre);
    rhL[tid] = r * hL[tid];
    __syncthreads();
    float hpre = xprow[512 + tid];
#pragma unroll 2
    for (int k = 0; k < 256; ++k) {
      hpre += fbL[k] * bf2f(kbf[k * 768 + 512 + tid]) + rhL[k] * bf2f(rkbf[k * 768 + 512 + tid]);
    }
    float z = hsig(zpre);
    float hh = tanhf(hpre);
    float hn = z * hL[tid] + (1.0f - z) * hh;
    y[(size_t)(b * 64 + t) * 256 + tid] = hn;
    __syncthreads();
    hL[tid] = hn;
    __syncthreads();
  };

  // big fused pass: logits = s@W_o1, p = exp(logits) (no max needed, |l|<=~7),
  // partial fb = p@emb, partial Z = sum p
  auto b_phase = [&]() {
    const int w = tid >> 6;
    const int lane = tid & 63;
    const int lq = lane >> 4;
    const int li = lane & 15;
    bf16x8 afr[8];
    {
      const unsigned short* ap = sbf + (16 * w + li) * 256 + lq * 8;
#pragma unroll
      for (int kk = 0; kk < 8; ++kk)
        afr[kk] = *reinterpret_cast<const bf16x8*>(ap + kk * 32);
    }
    floatx4 facc[16];
#pragma unroll
    for (int i = 0; i < 16; ++i) facc[i] = (floatx4){0.f, 0.f, 0.f, 0.f};
    float sacc[4] = {0.f, 0.f, 0.f, 0.f};
    short* myP = &Plds[w][0];

    for (int c = blk; c < NCHUNK; c += NBLK) {
      const int vbase = c * 64;
      floatx4 lacc[4];
#pragma unroll
      for (int n = 0; n < 4; ++n) lacc[n] = (floatx4){0.f, 0.f, 0.f, 0.f};
#pragma unroll
      for (int kk = 0; kk < 8; ++kk) {
#pragma unroll
        for (int n = 0; n < 4; ++n) {
          const unsigned short* bp =
              w1t + (size_t)(vbase + n * 16 + li) * 256 + kk * 32 + lq * 8;
          bf16x8 bfr = *reinterpret_cast<const bf16x8*>(bp);
          lacc[n] = __builtin_amdgcn_mfma_f32_16x16x32_bf16(afr[kk], bfr, lacc[n], 0, 0, 0);
        }
      }
#pragma unroll
      for (int n = 0; n < 4; ++n) {
        const int v = vbase + n * 16 + li;
        const bool ok = (v < VV);
#pragma unroll
        for (int q = 0; q < 4; ++q) {
          float p = ok ? __expf(lacc[n][q]) : 0.0f;
          sacc[q] += p;
          myP[(lq * 4 + q) * 88 + n * 16 + li] = (short)f2bf(p);
        }
      }
      __syncthreads();
#pragma unroll
      for (int k2 = 0; k2 < 2; ++k2) {
        bf16x8 pa = *reinterpret_cast<const bf16x8*>(myP + li * 88 + k2 * 32 + lq * 8);
#pragma unroll
        for (int dt = 0; dt < 16; ++dt) {
          const unsigned short* ep =
              embt + (size_t)(dt * 16 + li) * VPAD + vbase + k2 * 32 + lq * 8;
          bf16x8 ef = *reinterpret_cast<const bf16x8*>(ep);
          facc[dt] = __builtin_amdgcn_mfma_f32_16x16x32_bf16(pa, ef, facc[dt], 0, 0, 0);
        }
      }
      __syncthreads();
    }
    {
      unsigned short* op = pfb + (size_t)blk * 16384;
#pragma unroll
      for (int dt = 0; dt < 16; ++dt) {
#pragma unroll
        for (int q = 0; q < 4; ++q) {
          int row = 16 * w + lq * 4 + q;
          op[row * 256 + dt * 16 + li] = f2bf(facc[dt][q]);
        }
      }
    }
#pragma unroll
    for (int q = 0; q < 4; ++q) {
      float s = sacc[q];
      s += __shfl_xor(s, 1);
      s += __shfl_xor(s, 2);
      s += __shfl_xor(s, 4);
      s += __shfl_xor(s, 8);
      if (li == 0) psum[blk * 64 + 16 * w + lq * 4 + q] = s;
    }
  };

  // ---- t = 0 pre-phase: h = 0, compute s_0
  if (blk < BB) {
    hL[tid] = 0.0f;
    __syncthreads();
    attention();
  }
  gbar(bar);
  for (int t = 0; t < TT; ++t) {
    b_phase();
    gbar(bar);
    if (blk < BB) {
      ca_step(t);
      attention();
    }
    gbar(bar);
  }
}

// ---------------- host ----------------

extern "C" void kernel_launch(void* const* d_in, const int* in_sizes, int n_in,
                              void* d_out, int out_size, void* d_ws, size_t ws_size,
                              hipStream_t stream) {
  const float* x    = (const float*)d_in[0];
  const float* att  = (const float*)d_in[1];
  const float* kern = (const float*)d_in[2];
  const float* rk   = (const float*)d_in[3];
  const float* bias = (const float*)d_in[4];
  const float* aak  = (const float*)d_in[5];
  const float* aab  = (const float*)d_in[6];
  const float* w1   = (const float*)d_in[7];
  const float* emb  = (const float*)d_in[8];
  float* y = (float*)d_out;

  char* ws = (char*)d_ws;
  size_t o = 0;
  auto alloc = [&](size_t bytes) {
    char* p = ws + o;
    o += (bytes + 255) & ~(size_t)255;
    return p;
  };
  unsigned long long* bar = (unsigned long long*)alloc(256);
  unsigned short* w1t  = (unsigned short*)alloc((size_t)VPAD * 256 * 2);
  unsigned short* embt = (unsigned short*)alloc((size_t)256 * VPAD * 2);
  unsigned short* kbf  = (unsigned short*)alloc((size_t)196608 * 2);
  unsigned short* rkbf = (unsigned short*)alloc((size_t)196608 * 2);
  unsigned short* aabf = (unsigned short*)alloc((size_t)131072 * 2);
  float* xp  = (float*)alloc((size_t)4096 * 768 * 4);
  unsigned short* sbf = (unsigned short*)alloc((size_t)64 * 256 * 2);
  unsigned short* pfb = (unsigned short*)alloc((size_t)NBLK * 64 * 256 * 2);
  float* psum = (float*)alloc((size_t)NBLK * 64 * 4);
  (void)ws_size; (void)in_sizes; (void)n_in; (void)out_size;

  hipMemsetAsync(bar, 0, 256, stream);
  hipLaunchKernelGGL(k_f2bf, dim3(768), dim3(256), 0, stream, kern, kbf, 196608);
  hipLaunchKernelGGL(k_f2bf, dim3(768), dim3(256), 0, stream, rk, rkbf, 196608);
  hipLaunchKernelGGL(k_f2bf, dim3(512), dim3(256), 0, stream, aak, aabf, 131072);
  hipLaunchKernelGGL(k_tw1, dim3(1571, 8), dim3(32, 8), 0, stream, w1, w1t);
  hipLaunchKernelGGL(k_temb, dim3(1571, 8), dim3(32, 8), 0, stream, emb, embt);
  hipLaunchKernelGGL(k_xp, dim3(256), dim3(256), 0, stream, x, kern, bias, xp);
  hipLaunchKernelGGL(gru_main, dim3(NBLK), dim3(256), 0, stream,
                     att, aab, kbf, rkbf, aabf, xp, w1t, embt, sbf, pfb, psum, bar, y);
}